// Round 5
// baseline (1908.707 us; speedup 1.0000x reference)
//
#include <hip/hip_runtime.h>
#include <math.h>

#define DIM 512
#define NE 4096
#define NROWS 65536
#define PSTR 520                 // halves per panel row (512 + 8 pad)

typedef __attribute__((ext_vector_type(8))) short short8;
typedef __attribute__((ext_vector_type(4))) float f32x4;

// ---- bf16 helpers (round-to-nearest-even) ----
__device__ inline unsigned short f2bf(float f) {
    union { float f; unsigned int u; } v; v.f = f;
    unsigned int u = v.u;
    return (unsigned short)((u + 0x7fffu + ((u >> 16) & 1u)) >> 16);
}
__device__ inline float bf2f(unsigned short h) {
    union { unsigned int u; float f; } v; v.u = ((unsigned int)h) << 16;
    return v.f;
}
__device__ inline short hi_bf(float f) { return (short)f2bf(f); }
__device__ inline short lo_bf(float f) {
    unsigned short h = f2bf(f);
    return (short)f2bf(f - bf2f(h));
}

// ---------------- codebook column norms (fp32, proven R1) ----------------
__global__ void norms_kernel(const float* __restrict__ embed, float* __restrict__ norms) {
    int e = blockIdx.x * blockDim.x + threadIdx.x;
    if (e < NE) {
        float s = 0.f;
        #pragma unroll 8
        for (int d = 0; d < DIM; ++d) {
            float v = embed[(size_t)d * NE + e];
            s += v * v;
        }
        norms[e] = s;
    }
}

// ---------------- transpose + hi/lo bf16 split: eh[4096][512], el[4096][512] ----------------
__global__ void prep_kernel(const float* __restrict__ embed,
                            unsigned short* __restrict__ eh,
                            unsigned short* __restrict__ el) {
    __shared__ float t[64][65];
    const int tid = threadIdx.x;                 // 256
    const int e0 = blockIdx.x * 64;              // 64 blocks
    const int d0 = blockIdx.y * 64;              // 8 blocks
    for (int i = tid; i < 4096; i += 256) {
        int r = i >> 6, c = i & 63;              // r: d, c: e  (coalesced in e)
        t[r][c] = embed[(size_t)(d0 + r) * NE + e0 + c];
    }
    __syncthreads();
    for (int i = tid; i < 4096; i += 256) {
        int r = i >> 6, c = i & 63;              // r: e, c: d  (coalesced in d)
        float v = t[c][r];
        size_t off = (size_t)(e0 + r) * DIM + (d0 + c);
        unsigned short h = f2bf(v);
        eh[off] = h;
        el[off] = f2bf(v - bf2f(h));
    }
}

// ---------------- main: 3-pass bf16 MFMA scan, reg-prefetch pipeline, top-2 + rescore ----------------
__global__ __launch_bounds__(512, 2) void vq_main(
        const float* __restrict__ x,
        const unsigned short* __restrict__ eh,
        const unsigned short* __restrict__ el,
        const float* __restrict__ norms,
        float* __restrict__ out_idx,
        int* __restrict__ idx_ws) {

    __shared__ unsigned short ph[64 * PSTR];     // 66560 B
    __shared__ unsigned short pl[64 * PSTR];     // 66560 B
    __shared__ float b1v[128], b2v[128];
    __shared__ int   b1i[128], b2i[128];

    const int tid = threadIdx.x;
    const int w   = tid >> 6;                    // wave 0..7
    const int l   = tid & 63;
    const int lr  = l & 15;
    const int lg  = l >> 4;
    const int row0 = blockIdx.x * 128;

    // A fragments: lane holds A[row=l&15][k=(l>>4)*8 + j], hi+lo split (verbatim R3)
    short8 ah[16], al[16];
    {
        const float* xp = x + (size_t)(row0 + w * 16 + lr) * DIM + lg * 8;
        #pragma unroll
        for (int ks = 0; ks < 16; ++ks) {
            float4 u  = *(const float4*)(xp + ks * 32);
            float4 v2 = *(const float4*)(xp + ks * 32 + 4);
            short8 h, lo;
            h[0]=hi_bf(u.x);  h[1]=hi_bf(u.y);  h[2]=hi_bf(u.z);  h[3]=hi_bf(u.w);
            h[4]=hi_bf(v2.x); h[5]=hi_bf(v2.y); h[6]=hi_bf(v2.z); h[7]=hi_bf(v2.w);
            lo[0]=lo_bf(u.x);  lo[1]=lo_bf(u.y);  lo[2]=lo_bf(u.z);  lo[3]=lo_bf(u.w);
            lo[4]=lo_bf(v2.x); lo[5]=lo_bf(v2.y); lo[6]=lo_bf(v2.z); lo[7]=lo_bf(v2.w);
            ah[ks] = h; al[ks] = lo;
        }
    }

    float t1v[4], t2v[4]; int t1i[4], t2i[4];
    #pragma unroll
    for (int r = 0; r < 4; ++r) { t1v[r]=INFINITY; t2v[r]=INFINITY; t1i[r]=0x7fffffff; t2i[r]=0x7fffffff; }

    // staging: thread covers 8 chunks of 16B per panel; chunk j is 8KB-contiguous
    // across the block (coalesced global load, contiguous ds_write per wave row).
    // panel halves offset for chunk j: j*4096 + tid*8  -> row j*8+w, in-row l*8.
    uint4 rh[8], rl[8];
    #pragma unroll
    for (int j = 0; j < 8; ++j) {
        rh[j] = *(const uint4*)&eh[(size_t)j * 4096 + tid * 8];
        rl[j] = *(const uint4*)&el[(size_t)j * 4096 + tid * 8];
    }

    #pragma unroll 1
    for (int ct = 0; ct < 64; ++ct) {
        // write staged panel (LDS free: prior iteration's reads drained at its end barrier)
        #pragma unroll
        for (int j = 0; j < 8; ++j) {
            *(uint4*)&ph[(j * 8 + w) * PSTR + l * 8] = rh[j];
            *(uint4*)&pl[(j * 8 + w) * PSTR + l * 8] = rl[j];
        }
        __syncthreads();

        // prefetch next panel into registers (latency hides under compute below)
        if (ct < 63) {
            const size_t base = (size_t)(ct + 1) * 32768 + tid * 8;
            #pragma unroll
            for (int j = 0; j < 8; ++j) {
                rh[j] = *(const uint4*)&eh[base + (size_t)j * 4096];
                rl[j] = *(const uint4*)&el[base + (size_t)j * 4096];
            }
        }

        f32x4 acc[4];
        #pragma unroll
        for (int cb = 0; cb < 4; ++cb) acc[cb] = (f32x4){0.f, 0.f, 0.f, 0.f};

        #pragma unroll
        for (int ks = 0; ks < 16; ++ks) {
            #pragma unroll
            for (int cb = 0; cb < 4; ++cb) {
                int off = (cb * 16 + lr) * PSTR + ks * 32 + lg * 8;
                short8 bh = *(const short8*)&ph[off];
                short8 bl = *(const short8*)&pl[off];
                acc[cb] = __builtin_amdgcn_mfma_f32_16x16x32_bf16(ah[ks], bh, acc[cb], 0, 0, 0);
                acc[cb] = __builtin_amdgcn_mfma_f32_16x16x32_bf16(al[ks], bh, acc[cb], 0, 0, 0);
                acc[cb] = __builtin_amdgcn_mfma_f32_16x16x32_bf16(ah[ks], bl, acc[cb], 0, 0, 0);
            }
        }

        // s = ||e||^2 - 2*dot ; insert into per-row top-2 (ascending e order)
        #pragma unroll
        for (int cb = 0; cb < 4; ++cb) {
            int e = ct * 64 + cb * 16 + lr;
            float nrm = norms[e];
            #pragma unroll
            for (int r = 0; r < 4; ++r) {
                float s = fmaf(-2.0f, acc[cb][r], nrm);
                if (s < t1v[r]) { t2v[r]=t1v[r]; t2i[r]=t1i[r]; t1v[r]=s; t1i[r]=e; }
                else if (s < t2v[r]) { t2v[r]=s; t2i[r]=e; }
            }
        }
        __syncthreads();   // all panel reads drained before next ct's ds_write
    }

    // butterfly top-2 merge across 16 lanes per row group (lexicographic (v,i))
    #pragma unroll
    for (int m = 1; m < 16; m <<= 1) {
        #pragma unroll
        for (int r = 0; r < 4; ++r) {
            float o1v = __shfl_xor(t1v[r], m, 64);
            int   o1i = __shfl_xor(t1i[r], m, 64);
            float o2v = __shfl_xor(t2v[r], m, 64);
            int   o2i = __shfl_xor(t2i[r], m, 64);
            bool ofirst = (o1v < t1v[r]) || (o1v == t1v[r] && o1i < t1i[r]);
            float n1v, c1v, c2v; int n1i, c1i, c2i;
            if (ofirst) { n1v=o1v; n1i=o1i; c1v=t1v[r]; c1i=t1i[r]; c2v=o2v; c2i=o2i; }
            else        { n1v=t1v[r]; n1i=t1i[r]; c1v=o1v; c1i=o1i; c2v=t2v[r]; c2i=t2i[r]; }
            bool cfirst = (c1v < c2v) || (c1v == c2v && c1i < c2i);
            t1v[r] = n1v; t1i[r] = n1i;
            t2v[r] = cfirst ? c1v : c2v; t2i[r] = cfirst ? c1i : c2i;
        }
    }
    if (lr == 0) {
        #pragma unroll
        for (int r = 0; r < 4; ++r) {
            int rowloc = w * 16 + lg * 4 + r;
            b1v[rowloc] = t1v[r]; b1i[rowloc] = t1i[r];
            b2v[rowloc] = t2v[r]; b2i[rowloc] = t2i[r];
        }
    }
    __syncthreads();

    // exact-precision rescore of both candidates via hi+lo reconstruction
    #pragma unroll 1
    for (int rr = 0; rr < 16; ++rr) {
        int rowloc = w * 16 + rr;
        int i1 = b1i[rowloc], i2 = b2i[rowloc];
        const float* xr = x + (size_t)(row0 + rowloc) * DIM + l * 8;
        float4 xa = *(const float4*)xr, xb = *(const float4*)(xr + 4);
        uint4 h1 = *(const uint4*)&eh[(size_t)i1 * DIM + l * 8];
        uint4 l1 = *(const uint4*)&el[(size_t)i1 * DIM + l * 8];
        uint4 h2 = *(const uint4*)&eh[(size_t)i2 * DIM + l * 8];
        uint4 l2 = *(const uint4*)&el[(size_t)i2 * DIM + l * 8];
        const unsigned short* hp1 = (const unsigned short*)&h1;
        const unsigned short* lp1 = (const unsigned short*)&l1;
        const unsigned short* hp2 = (const unsigned short*)&h2;
        const unsigned short* lp2 = (const unsigned short*)&l2;
        float xv[8] = {xa.x, xa.y, xa.z, xa.w, xb.x, xb.y, xb.z, xb.w};
        float d1 = 0.f, d2 = 0.f;
        #pragma unroll
        for (int j = 0; j < 8; ++j) {
            d1 += xv[j] * (bf2f(hp1[j]) + bf2f(lp1[j]));
            d2 += xv[j] * (bf2f(hp2[j]) + bf2f(lp2[j]));
        }
        #pragma unroll
        for (int m = 32; m >= 1; m >>= 1) {
            d1 += __shfl_xor(d1, m, 64);
            d2 += __shfl_xor(d2, m, 64);
        }
        if (l == 0) {
            float s1 = norms[i1] - 2.0f * d1;
            float s2 = norms[i2] - 2.0f * d2;
            int win = (s2 < s1 || (s2 == s1 && i2 < i1)) ? i2 : i1;
            out_idx[row0 + rowloc] = (float)win;
            idx_ws[row0 + rowloc] = win;
        }
    }
}

// ---------------- gather + diff partials (hi+lo reconstruct) ----------------
__global__ void gather_kernel(const float* __restrict__ x,
                              const unsigned short* __restrict__ eh,
                              const unsigned short* __restrict__ el,
                              const int* __restrict__ idx, float* __restrict__ out_q,
                              float* __restrict__ partial) {
    __shared__ float red[256];
    const int tid = threadIdx.x;
    float local = 0.f;
    #pragma unroll 1
    for (int j = 0; j < 8; ++j) {
        int o8 = blockIdx.x * 2048 + j * 256 + tid;   // octet unit
        int r  = o8 >> 6;                             // 64 octets per row
        int c8 = o8 & 63;
        int e  = idx[r];
        uint4 hv = *(const uint4*)&eh[(size_t)e * DIM + c8 * 8];
        uint4 lv = *(const uint4*)&el[(size_t)e * DIM + c8 * 8];
        const unsigned short* hp = (const unsigned short*)&hv;
        const unsigned short* lp = (const unsigned short*)&lv;
        float q[8];
        #pragma unroll
        for (int k = 0; k < 8; ++k) q[k] = bf2f(hp[k]) + bf2f(lp[k]);
        float4 xa = *(const float4*)&x[(size_t)r * DIM + c8 * 8];
        float4 xb = *(const float4*)&x[(size_t)r * DIM + c8 * 8 + 4];
        *(float4*)&out_q[(size_t)r * DIM + c8 * 8]     = make_float4(q[0], q[1], q[2], q[3]);
        *(float4*)&out_q[(size_t)r * DIM + c8 * 8 + 4] = make_float4(q[4], q[5], q[6], q[7]);
        float xs[8] = {xa.x, xa.y, xa.z, xa.w, xb.x, xb.y, xb.z, xb.w};
        #pragma unroll
        for (int k = 0; k < 8; ++k) { float t = q[k] - xs[k]; local += t * t; }
    }
    red[tid] = local;
    __syncthreads();
    for (int s = 128; s > 0; s >>= 1) {
        if (tid < s) red[tid] += red[tid + s];
        __syncthreads();
    }
    if (tid == 0) partial[blockIdx.x] = red[0];
}

// ---------------- deterministic diff reduction ----------------
__global__ void diff_kernel(const float* __restrict__ partial, float* __restrict__ out_diff) {
    __shared__ float red[256];
    float s = 0.f;
    for (int i = threadIdx.x; i < 2048; i += 256) s += partial[i];
    red[threadIdx.x] = s;
    __syncthreads();
    for (int st = 128; st > 0; st >>= 1) {
        if (threadIdx.x < st) red[threadIdx.x] += red[threadIdx.x + st];
        __syncthreads();
    }
    if (threadIdx.x == 0)
        out_diff[0] = red[0] * (1.0f / ((float)NROWS * (float)DIM));
}

// ================= fallback path (R1, proven; needs only 24 KB ws) =================
#define BM 32
#define BN 64
#define BK 16
__global__ __launch_bounds__(256) void vq_kernel_fb(
        const float* __restrict__ x, const float* __restrict__ embed,
        const float* __restrict__ norms, float* __restrict__ out_q,
        float* __restrict__ out_idx, float* __restrict__ partial) {
    __shared__ float xs[BM][BK + 1];
    __shared__ float es[BK][BN];
    __shared__ float rv[BM][17];
    __shared__ int   ri[BM][17];
    __shared__ float bestv[BM];
    __shared__ int   besti[BM];
    __shared__ float red[256];
    const int tid = threadIdx.x;
    const int tc  = tid & 15;
    const int tr  = tid >> 4;
    const int row0 = blockIdx.x * BM;
    if (tid < BM) { bestv[tid] = INFINITY; besti[tid] = 0; }
    __syncthreads();
    for (int ct = 0; ct < NE / BN; ++ct) {
        float acc[2][4] = {{0.f,0.f,0.f,0.f},{0.f,0.f,0.f,0.f}};
        for (int k0 = 0; k0 < DIM; k0 += BK) {
            {
                int r = tid >> 3;
                int k = (tid & 7) * 2;
                const float* src = &x[(size_t)(row0 + r) * DIM + k0 + k];
                xs[r][k] = src[0]; xs[r][k + 1] = src[1];
            }
            {
                int r = tid >> 4;
                int c = (tid & 15) * 4;
                float4 v = *(const float4*)&embed[(size_t)(k0 + r) * NE + ct * BN + c];
                *(float4*)&es[r][c] = v;
            }
            __syncthreads();
            #pragma unroll
            for (int kk = 0; kk < BK; ++kk) {
                float a0 = xs[tr * 2 + 0][kk];
                float a1 = xs[tr * 2 + 1][kk];
                float4 b = *(const float4*)&es[kk][tc * 4];
                acc[0][0] += a0 * b.x; acc[0][1] += a0 * b.y;
                acc[0][2] += a0 * b.z; acc[0][3] += a0 * b.w;
                acc[1][0] += a1 * b.x; acc[1][1] += a1 * b.y;
                acc[1][2] += a1 * b.z; acc[1][3] += a1 * b.w;
            }
            __syncthreads();
        }
        #pragma unroll
        for (int i = 0; i < 2; ++i) {
            float bv = INFINITY; int bj = 0;
            #pragma unroll
            for (int j = 0; j < 4; ++j) {
                int e = ct * BN + tc * 4 + j;
                float s = norms[e] - 2.0f * acc[i][j];
                if (s < bv) { bv = s; bj = e; }
            }
            rv[tr * 2 + i][tc] = bv; ri[tr * 2 + i][tc] = bj;
        }
        __syncthreads();
        if (tid < BM) {
            float bv = bestv[tid]; int bi = besti[tid];
            #pragma unroll
            for (int t = 0; t < 16; ++t) {
                float v = rv[tid][t];
                if (v < bv) { bv = v; bi = ri[tid][t]; }
            }
            bestv[tid] = bv; besti[tid] = bi;
        }
        __syncthreads();
    }
    if (tid < BM) out_idx[row0 + tid] = (float)besti[tid];
    __syncthreads();
    float local = 0.f;
    for (int i = tid; i < BM * DIM; i += 256) {
        int r = i >> 9;
        int d = i & (DIM - 1);
        int e = besti[r];
        float q  = embed[(size_t)d * NE + e];
        float xv = x[(size_t)(row0 + r) * DIM + d];
        out_q[(size_t)(row0 + r) * DIM + d] = q;
        float t = q - xv;
        local += t * t;
    }
    red[tid] = local;
    __syncthreads();
    for (int s = 128; s > 0; s >>= 1) {
        if (tid < s) red[tid] += red[tid + s];
        __syncthreads();
    }
    if (tid == 0) partial[blockIdx.x] = red[0];
}

extern "C" void kernel_launch(void* const* d_in, const int* in_sizes, int n_in,
                              void* d_out, int out_size, void* d_ws, size_t ws_size,
                              hipStream_t stream) {
    (void)in_sizes; (void)n_in; (void)out_size;
    const float* x     = (const float*)d_in[0];
    const float* embed = (const float*)d_in[1];

    float* out      = (float*)d_out;
    float* out_q    = out;
    float* out_diff = out + (size_t)NROWS * DIM;
    float* out_idx  = out_diff + 1;

    const size_t NEED = 4194304ull * 2 + 16384 + 8192 + 262144;  // eh+el+norms+partial+idx

    char* wsb = (char*)d_ws;
    if (ws_size >= NEED) {
        unsigned short* eh      = (unsigned short*)wsb;               // 4194304 B
        unsigned short* el      = (unsigned short*)(wsb + 4194304);   // 4194304 B
        float*          norms   = (float*)(wsb + 8388608);            //   16384 B
        float*          partial = (float*)(wsb + 8404992);            //    8192 B
        int*            idx     = (int*)(wsb + 8413184);              //  262144 B

        norms_kernel<<<NE / 256, 256, 0, stream>>>(embed, norms);
        prep_kernel<<<dim3(64, 8), 256, 0, stream>>>(embed, eh, el);
        vq_main<<<512, 512, 0, stream>>>(x, eh, el, norms, out_idx, idx);
        gather_kernel<<<2048, 256, 0, stream>>>(x, eh, el, idx, out_q, partial);
        diff_kernel<<<1, 256, 0, stream>>>(partial, out_diff);
    } else {
        float* norms   = (float*)wsb;            // 16384 B
        float* partial = norms + NE;             //  8192 B
        norms_kernel<<<NE / 256, 256, 0, stream>>>(embed, norms);
        vq_kernel_fb<<<NROWS / BM, 256, 0, stream>>>(x, embed, norms, out_q, out_idx, partial);
        diff_kernel<<<1, 256, 0, stream>>>(partial, out_diff);
    }
}

// Round 6
// 650.183 us; speedup vs baseline: 2.9356x; 2.9356x over previous
//
#include <hip/hip_runtime.h>
#include <math.h>

#define DIM 512
#define NE 4096
#define NROWS 65536
#define MARGIN 0.6f            // ~12 sigma of single-bf16 scan noise

typedef __attribute__((ext_vector_type(8))) short short8;
typedef __attribute__((ext_vector_type(4))) float f32x4;

// ---- bf16 helpers (round-to-nearest-even) ----
__device__ inline unsigned short f2bf(float f) {
    union { float f; unsigned int u; } v; v.f = f;
    unsigned int u = v.u;
    return (unsigned short)((u + 0x7fffu + ((u >> 16) & 1u)) >> 16);
}
__device__ inline float bf2f(unsigned short h) {
    union { unsigned int u; float f; } v; v.u = ((unsigned int)h) << 16;
    return v.f;
}
__device__ inline short hi_bf(float f) { return (short)f2bf(f); }

// lexicographic (value, index) less-than
__device__ inline bool lexlt(float v1, int i1, float v2, int i2) {
    return (v1 < v2) || (v1 == v2 && i1 < i2);
}

// ---------------- codebook column norms (fp32, proven R1) ----------------
__global__ void norms_kernel(const float* __restrict__ embed, float* __restrict__ norms) {
    int e = blockIdx.x * blockDim.x + threadIdx.x;
    if (e < NE) {
        float s = 0.f;
        #pragma unroll 8
        for (int d = 0; d < DIM; ++d) {
            float v = embed[(size_t)d * NE + e];
            s += v * v;
        }
        norms[e] = s;
    }
}

// ---------------- transpose + hi/lo bf16 split: eh[4096][512], el[4096][512] ----------------
__global__ void prep_kernel(const float* __restrict__ embed,
                            unsigned short* __restrict__ eh,
                            unsigned short* __restrict__ el) {
    __shared__ float t[64][65];
    const int tid = threadIdx.x;                 // 256
    const int e0 = blockIdx.x * 64;              // 64 blocks
    const int d0 = blockIdx.y * 64;              // 8 blocks
    for (int i = tid; i < 4096; i += 256) {
        int r = i >> 6, c = i & 63;              // r: d, c: e  (coalesced in e)
        t[r][c] = embed[(size_t)(d0 + r) * NE + e0 + c];
    }
    __syncthreads();
    for (int i = tid; i < 4096; i += 256) {
        int r = i >> 6, c = i & 63;              // r: e, c: d  (coalesced in d)
        float v = t[c][r];
        size_t off = (size_t)(e0 + r) * DIM + (d0 + c);
        unsigned short h = f2bf(v);
        eh[off] = h;
        el[off] = f2bf(v - bf2f(h));
    }
}

// ---------------- main: 1-pass bf16 MFMA scan (32 rows/wave, swizzled dbuf LDS),
//                  per-lane top-2 -> global top-4 -> margin-gated exact rescore ----
__global__ __launch_bounds__(512, 2) void vq_main(
        const float* __restrict__ x,
        const unsigned short* __restrict__ eh,
        const unsigned short* __restrict__ el,
        const float* __restrict__ norms,
        float* __restrict__ out_idx,
        int* __restrict__ idx_ws) {

    __shared__ unsigned short ph[2][64 * 512];   // 2 x 65536 B, granule-swizzled
    __shared__ int   bi4[256][4];
    __shared__ float bgap[256];

    const int tid = threadIdx.x;
    const int w   = tid >> 6;                    // wave 0..7
    const int l   = tid & 63;
    const int lr  = l & 15;
    const int lg  = l >> 4;
    const int row0 = blockIdx.x * 256;

    // ---- A fragments: 2 rowsets x 16 ks, single bf16 ----
    short8 a[2][16];
    #pragma unroll
    for (int s = 0; s < 2; ++s) {
        const float* xp = x + (size_t)(row0 + w * 32 + s * 16 + lr) * DIM + lg * 8;
        #pragma unroll
        for (int ks = 0; ks < 16; ++ks) {
            float4 u  = *(const float4*)(xp + ks * 32);
            float4 v2 = *(const float4*)(xp + ks * 32 + 4);
            short8 h;
            h[0]=hi_bf(u.x);  h[1]=hi_bf(u.y);  h[2]=hi_bf(u.z);  h[3]=hi_bf(u.w);
            h[4]=hi_bf(v2.x); h[5]=hi_bf(v2.y); h[6]=hi_bf(v2.z); h[7]=hi_bf(v2.w);
            a[s][ks] = h;
        }
    }

    float t1v[2][4], t2v[2][4]; int t1i[2][4], t2i[2][4];
    #pragma unroll
    for (int s = 0; s < 2; ++s)
        #pragma unroll
        for (int r = 0; r < 4; ++r) {
            t1v[s][r]=INFINITY; t2v[s][r]=INFINITY;
            t1i[s][r]=0x7ffffffe; t2i[s][r]=0x7fffffff;
        }

    // ---- stage panel 0 (granule (c,o=l) -> LDS c*512 + (o^(c&7))*16B) ----
    #pragma unroll
    for (int j = 0; j < 8; ++j) {
        int c = w + 8 * j;
        uint4 v = *(const uint4*)&eh[(size_t)c * DIM + l * 8];
        *(uint4*)&ph[0][c * 512 + ((l ^ (c & 7)) * 8)] = v;
    }
    __syncthreads();

    #pragma unroll 1
    for (int ct = 0; ct < 64; ++ct) {
        const int cur = ct & 1;

        f32x4 acc[2][4];
        #pragma unroll
        for (int s = 0; s < 2; ++s)
            #pragma unroll
            for (int cb = 0; cb < 4; ++cb) acc[s][cb] = (f32x4){0.f,0.f,0.f,0.f};

        #pragma unroll
        for (int ks = 0; ks < 16; ++ks) {
            #pragma unroll
            for (int cb = 0; cb < 4; ++cb) {
                int off = (cb * 16 + lr) * 512 + (((ks * 4 + lg) ^ (lr & 7)) * 8);
                short8 bh = *(const short8*)&ph[cur][off];
                acc[0][cb] = __builtin_amdgcn_mfma_f32_16x16x32_bf16(a[0][ks], bh, acc[0][cb], 0, 0, 0);
                acc[1][cb] = __builtin_amdgcn_mfma_f32_16x16x32_bf16(a[1][ks], bh, acc[1][cb], 0, 0, 0);
            }
        }

        // stage loads for next panel (latency hides under epilogue VALU)
        uint4 st[8];
        if (ct < 63) {
            const unsigned short* src = eh + (size_t)(ct + 1) * 32768;
            #pragma unroll
            for (int j = 0; j < 8; ++j) {
                int c = w + 8 * j;
                st[j] = *(const uint4*)&src[(size_t)c * DIM + l * 8];
            }
        }

        // epilogue: s = ||e||^2 - 2*dot ; per-lane top-2 (ascending e)
        #pragma unroll
        for (int cb = 0; cb < 4; ++cb) {
            int e = ct * 64 + cb * 16 + lr;
            float nrm = norms[e];
            #pragma unroll
            for (int s = 0; s < 2; ++s)
                #pragma unroll
                for (int r = 0; r < 4; ++r) {
                    float sv = fmaf(-2.0f, acc[s][cb][r], nrm);
                    if (sv < t1v[s][r]) { t2v[s][r]=t1v[s][r]; t2i[s][r]=t1i[s][r]; t1v[s][r]=sv; t1i[s][r]=e; }
                    else if (sv < t2v[s][r]) { t2v[s][r]=sv; t2i[s][r]=e; }
                }
        }

        if (ct < 63) {
            #pragma unroll
            for (int j = 0; j < 8; ++j) {
                int c = w + 8 * j;
                *(uint4*)&ph[cur ^ 1][c * 512 + ((l ^ (c & 7)) * 8)] = st[j];
            }
        }
        __syncthreads();
    }

    // ---- per-slot: butterfly-merge per-lane top-2 lists into global top-4 ----
    #pragma unroll
    for (int s = 0; s < 2; ++s) {
        #pragma unroll
        for (int r = 0; r < 4; ++r) {
            float av[4] = { t1v[s][r], t2v[s][r], INFINITY, INFINITY };
            int   ai[4] = { t1i[s][r], t2i[s][r], 0x7ffffffe, 0x7fffffff };
            #pragma unroll
            for (int m = 1; m < 16; m <<= 1) {
                float bv[4]; int bi_[4];
                #pragma unroll
                for (int q = 0; q < 4; ++q) {
                    bv[q]  = __shfl_xor(av[q], m, 64);
                    bi_[q] = __shfl_xor(ai[q], m, 64);
                }
                float cv[4]; int ci[4];
                #pragma unroll
                for (int q = 0; q < 4; ++q) {
                    bool t = lexlt(av[q], ai[q], bv[3 - q], bi_[3 - q]);
                    cv[q] = t ? av[q] : bv[3 - q];
                    ci[q] = t ? ai[q] : bi_[3 - q];
                }
                // bitonic sort-4: CE(0,2) CE(1,3) CE(0,1) CE(2,3)
                #define CE(A,B) { if (!lexlt(cv[A],ci[A],cv[B],ci[B])) { \
                    float tv=cv[A]; cv[A]=cv[B]; cv[B]=tv; int ti=ci[A]; ci[A]=ci[B]; ci[B]=ti; } }
                CE(0,2) CE(1,3) CE(0,1) CE(2,3)
                #undef CE
                #pragma unroll
                for (int q = 0; q < 4; ++q) { av[q] = cv[q]; ai[q] = ci[q]; }
            }
            if (lr == 0) {
                int rowloc = w * 32 + s * 16 + lg * 4 + r;
                #pragma unroll
                for (int q = 0; q < 4; ++q) bi4[rowloc][q] = ai[q];
                bgap[rowloc] = av[1] - av[0];
            }
        }
    }
    __syncthreads();

    // ---- margin-gated exact rescore (x fp32, e = hi+lo) of the 4 candidates ----
    #pragma unroll 1
    for (int rr = 0; rr < 32; ++rr) {
        int rowloc = w * 32 + rr;
        int grow = row0 + rowloc;
        float gap = bgap[rowloc];
        int c0 = bi4[rowloc][0] & (NE - 1);
        if (gap > MARGIN) {
            if (l == 0) { out_idx[grow] = (float)c0; idx_ws[grow] = c0; }
            continue;
        }
        int cand[4];
        cand[0] = c0;
        cand[1] = bi4[rowloc][1] & (NE - 1);
        cand[2] = bi4[rowloc][2] & (NE - 1);
        cand[3] = bi4[rowloc][3] & (NE - 1);

        const float* xr = x + (size_t)grow * DIM + l * 8;
        float4 xa = *(const float4*)xr, xb = *(const float4*)(xr + 4);
        float xv[8] = {xa.x, xa.y, xa.z, xa.w, xb.x, xb.y, xb.z, xb.w};

        float d[4];
        #pragma unroll
        for (int q = 0; q < 4; ++q) {
            uint4 hv = *(const uint4*)&eh[(size_t)cand[q] * DIM + l * 8];
            uint4 lv = *(const uint4*)&el[(size_t)cand[q] * DIM + l * 8];
            const unsigned short* hp = (const unsigned short*)&hv;
            const unsigned short* lp = (const unsigned short*)&lv;
            float acc = 0.f;
            #pragma unroll
            for (int j = 0; j < 8; ++j) acc += xv[j] * (bf2f(hp[j]) + bf2f(lp[j]));
            d[q] = acc;
        }
        #pragma unroll
        for (int m = 32; m >= 1; m >>= 1) {
            #pragma unroll
            for (int q = 0; q < 4; ++q) d[q] += __shfl_xor(d[q], m, 64);
        }
        if (l == 0) {
            float bs = norms[cand[0]] - 2.0f * d[0];
            int   bi = cand[0];
            #pragma unroll
            for (int q = 1; q < 4; ++q) {
                float sq = norms[cand[q]] - 2.0f * d[q];
                if (sq < bs || (sq == bs && cand[q] < bi)) { bs = sq; bi = cand[q]; }
            }
            out_idx[grow] = (float)bi;
            idx_ws[grow] = bi;
        }
    }
}

// ---------------- gather + diff partials (hi+lo reconstruct; proven R5) ----------------
__global__ void gather_kernel(const float* __restrict__ x,
                              const unsigned short* __restrict__ eh,
                              const unsigned short* __restrict__ el,
                              const int* __restrict__ idx, float* __restrict__ out_q,
                              float* __restrict__ partial) {
    __shared__ float red[256];
    const int tid = threadIdx.x;
    float local = 0.f;
    #pragma unroll 1
    for (int j = 0; j < 8; ++j) {
        int o8 = blockIdx.x * 2048 + j * 256 + tid;   // octet unit
        int r  = o8 >> 6;                             // 64 octets per row
        int c8 = o8 & 63;
        int e  = idx[r];
        uint4 hv = *(const uint4*)&eh[(size_t)e * DIM + c8 * 8];
        uint4 lv = *(const uint4*)&el[(size_t)e * DIM + c8 * 8];
        const unsigned short* hp = (const unsigned short*)&hv;
        const unsigned short* lp = (const unsigned short*)&lv;
        float q[8];
        #pragma unroll
        for (int k = 0; k < 8; ++k) q[k] = bf2f(hp[k]) + bf2f(lp[k]);
        float4 xa = *(const float4*)&x[(size_t)r * DIM + c8 * 8];
        float4 xb = *(const float4*)&x[(size_t)r * DIM + c8 * 8 + 4];
        *(float4*)&out_q[(size_t)r * DIM + c8 * 8]     = make_float4(q[0], q[1], q[2], q[3]);
        *(float4*)&out_q[(size_t)r * DIM + c8 * 8 + 4] = make_float4(q[4], q[5], q[6], q[7]);
        float xs[8] = {xa.x, xa.y, xa.z, xa.w, xb.x, xb.y, xb.z, xb.w};
        #pragma unroll
        for (int k = 0; k < 8; ++k) { float t = q[k] - xs[k]; local += t * t; }
    }
    red[tid] = local;
    __syncthreads();
    for (int s = 128; s > 0; s >>= 1) {
        if (tid < s) red[tid] += red[tid + s];
        __syncthreads();
    }
    if (tid == 0) partial[blockIdx.x] = red[0];
}

// ---------------- deterministic diff reduction ----------------
__global__ void diff_kernel(const float* __restrict__ partial, float* __restrict__ out_diff) {
    __shared__ float red[256];
    float s = 0.f;
    for (int i = threadIdx.x; i < 2048; i += 256) s += partial[i];
    red[threadIdx.x] = s;
    __syncthreads();
    for (int st = 128; st > 0; st >>= 1) {
        if (threadIdx.x < st) red[threadIdx.x] += red[threadIdx.x + st];
        __syncthreads();
    }
    if (threadIdx.x == 0)
        out_diff[0] = red[0] * (1.0f / ((float)NROWS * (float)DIM));
}

// ================= fallback path (R1, proven; needs only 24 KB ws) =================
#define BM 32
#define BN 64
#define BK 16
__global__ __launch_bounds__(256) void vq_kernel_fb(
        const float* __restrict__ x, const float* __restrict__ embed,
        const float* __restrict__ norms, float* __restrict__ out_q,
        float* __restrict__ out_idx, float* __restrict__ partial) {
    __shared__ float xs[BM][BK + 1];
    __shared__ float es[BK][BN];
    __shared__ float rv[BM][17];
    __shared__ int   ri[BM][17];
    __shared__ float bestv[BM];
    __shared__ int   besti[BM];
    __shared__ float red[256];
    const int tid = threadIdx.x;
    const int tc  = tid & 15;
    const int tr  = tid >> 4;
    const int row0 = blockIdx.x * BM;
    if (tid < BM) { bestv[tid] = INFINITY; besti[tid] = 0; }
    __syncthreads();
    for (int ct = 0; ct < NE / BN; ++ct) {
        float acc[2][4] = {{0.f,0.f,0.f,0.f},{0.f,0.f,0.f,0.f}};
        for (int k0 = 0; k0 < DIM; k0 += BK) {
            {
                int r = tid >> 3;
                int k = (tid & 7) * 2;
                const float* src = &x[(size_t)(row0 + r) * DIM + k0 + k];
                xs[r][k] = src[0]; xs[r][k + 1] = src[1];
            }
            {
                int r = tid >> 4;
                int c = (tid & 15) * 4;
                float4 v = *(const float4*)&embed[(size_t)(k0 + r) * NE + ct * BN + c];
                *(float4*)&es[r][c] = v;
            }
            __syncthreads();
            #pragma unroll
            for (int kk = 0; kk < BK; ++kk) {
                float a0 = xs[tr * 2 + 0][kk];
                float a1 = xs[tr * 2 + 1][kk];
                float4 b = *(const float4*)&es[kk][tc * 4];
                acc[0][0] += a0 * b.x; acc[0][1] += a0 * b.y;
                acc[0][2] += a0 * b.z; acc[0][3] += a0 * b.w;
                acc[1][0] += a1 * b.x; acc[1][1] += a1 * b.y;
                acc[1][2] += a1 * b.z; acc[1][3] += a1 * b.w;
            }
            __syncthreads();
        }
        #pragma unroll
        for (int i = 0; i < 2; ++i) {
            float bv = INFINITY; int bj = 0;
            #pragma unroll
            for (int j = 0; j < 4; ++j) {
                int e = ct * BN + tc * 4 + j;
                float s = norms[e] - 2.0f * acc[i][j];
                if (s < bv) { bv = s; bj = e; }
            }
            rv[tr * 2 + i][tc] = bv; ri[tr * 2 + i][tc] = bj;
        }
        __syncthreads();
        if (tid < BM) {
            float bv = bestv[tid]; int bi = besti[tid];
            #pragma unroll
            for (int t = 0; t < 16; ++t) {
                float v = rv[tid][t];
                if (v < bv) { bv = v; bi = ri[tid][t]; }
            }
            bestv[tid] = bv; besti[tid] = bi;
        }
        __syncthreads();
    }
    if (tid < BM) out_idx[row0 + tid] = (float)besti[tid];
    __syncthreads();
    float local = 0.f;
    for (int i = tid; i < BM * DIM; i += 256) {
        int r = i >> 9;
        int d = i & (DIM - 1);
        int e = besti[r];
        float q  = embed[(size_t)d * NE + e];
        float xv = x[(size_t)(row0 + r) * DIM + d];
        out_q[(size_t)(row0 + r) * DIM + d] = q;
        float t = q - xv;
        local += t * t;
    }
    red[tid] = local;
    __syncthreads();
    for (int s = 128; s > 0; s >>= 1) {
        if (tid < s) red[tid] += red[tid + s];
        __syncthreads();
    }
    if (tid == 0) partial[blockIdx.x] = red[0];
}

extern "C" void kernel_launch(void* const* d_in, const int* in_sizes, int n_in,
                              void* d_out, int out_size, void* d_ws, size_t ws_size,
                              hipStream_t stream) {
    (void)in_sizes; (void)n_in; (void)out_size;
    const float* x     = (const float*)d_in[0];
    const float* embed = (const float*)d_in[1];

    float* out      = (float*)d_out;
    float* out_q    = out;
    float* out_diff = out + (size_t)NROWS * DIM;
    float* out_idx  = out_diff + 1;

    const size_t NEED = 4194304ull * 2 + 16384 + 8192 + 262144;  // eh+el+norms+partial+idx

    char* wsb = (char*)d_ws;
    if (ws_size >= NEED) {
        unsigned short* eh      = (unsigned short*)wsb;               // 4194304 B
        unsigned short* el      = (unsigned short*)(wsb + 4194304);   // 4194304 B
        float*          norms   = (float*)(wsb + 8388608);            //   16384 B
        float*          partial = (float*)(wsb + 8404992);            //    8192 B
        int*            idx     = (int*)(wsb + 8413184);              //  262144 B

        norms_kernel<<<NE / 256, 256, 0, stream>>>(embed, norms);
        prep_kernel<<<dim3(64, 8), 256, 0, stream>>>(embed, eh, el);
        vq_main<<<256, 512, 0, stream>>>(x, eh, el, norms, out_idx, idx);
        gather_kernel<<<2048, 256, 0, stream>>>(x, eh, el, idx, out_q, partial);
        diff_kernel<<<1, 256, 0, stream>>>(partial, out_diff);
    } else {
        float* norms   = (float*)wsb;            // 16384 B
        float* partial = norms + NE;             //  8192 B
        norms_kernel<<<NE / 256, 256, 0, stream>>>(embed, norms);
        vq_kernel_fb<<<NROWS / BM, 256, 0, stream>>>(x, embed, norms, out_q, out_idx, partial);
        diff_kernel<<<1, 256, 0, stream>>>(partial, out_diff);
    }
}

// Round 7
// 433.699 us; speedup vs baseline: 4.4010x; 1.4992x over previous
//
#include <hip/hip_runtime.h>
#include <math.h>

#define DIM 512
#define NE 4096
#define NROWS 65536
#define MARGIN 0.6f            // ~12 sigma of single-bf16 scan noise

typedef __attribute__((ext_vector_type(8))) short short8;
typedef __attribute__((ext_vector_type(4))) float f32x4;

// ---- bf16 helpers (round-to-nearest-even) ----
__device__ inline unsigned short f2bf(float f) {
    union { float f; unsigned int u; } v; v.f = f;
    unsigned int u = v.u;
    return (unsigned short)((u + 0x7fffu + ((u >> 16) & 1u)) >> 16);
}
__device__ inline float bf2f(unsigned short h) {
    union { unsigned int u; float f; } v; v.u = ((unsigned int)h) << 16;
    return v.f;
}
__device__ inline short hi_bf(float f) { return (short)f2bf(f); }

__device__ inline bool lexlt(float v1, int i1, float v2, int i2) {
    return (v1 < v2) || (v1 == v2 && i1 < i2);
}

// ---- async global->LDS (16B/lane; LDS dest = wave-uniform base + lane*16) ----
typedef __attribute__((address_space(1))) const void gconst_t;
typedef __attribute__((address_space(3))) void ldsv_t;
__device__ __forceinline__ void gload_lds16(const void* g, void* l) {
    __builtin_amdgcn_global_load_lds((gconst_t*)g, (ldsv_t*)l, 16, 0, 0);
}

// ---------------- codebook column norms (fp32, proven R1) ----------------
__global__ void norms_kernel(const float* __restrict__ embed, float* __restrict__ norms) {
    int e = blockIdx.x * blockDim.x + threadIdx.x;
    if (e < NE) {
        float s = 0.f;
        #pragma unroll 8
        for (int d = 0; d < DIM; ++d) {
            float v = embed[(size_t)d * NE + e];
            s += v * v;
        }
        norms[e] = s;
    }
}

// ---------------- transpose + hi/lo split ----------------
// ehs: swizzled image — ehs[e*512 + (((d>>3) ^ (e&7))<<3) + (d&7)] = hi(embed[d][e])
//      (so byte-linear DMA of a 64-code panel lands the XOR-swizzled LDS layout)
// el : linear — el[e*512 + d] = lo(embed[d][e])
__global__ void prep_kernel(const float* __restrict__ embed,
                            unsigned short* __restrict__ ehs,
                            unsigned short* __restrict__ el) {
    __shared__ float t[64][65];
    const int tid = threadIdx.x;                 // 256
    const int e0 = blockIdx.x * 64;              // 64 blocks
    const int d0 = blockIdx.y * 64;              // 8 blocks
    for (int i = tid; i < 4096; i += 256) {
        int r = i >> 6, c = i & 63;              // r: d, c: e  (coalesced in e)
        t[r][c] = embed[(size_t)(d0 + r) * NE + e0 + c];
    }
    __syncthreads();
    for (int i = tid; i < 4096; i += 256) {
        int r = i >> 6, c = i & 63;              // r: e, c: d  (coalesced in d)
        float v = t[c][r];
        int e = e0 + r, d = d0 + c;
        unsigned short h = f2bf(v);
        ehs[(size_t)e * 512 + ((((d >> 3) ^ (e & 7)) << 3) | (d & 7))] = h;
        el[(size_t)e * 512 + d] = f2bf(v - bf2f(h));
    }
}

// ---------------- main: 1-pass bf16 MFMA scan, DMA-staged swizzled dbuf LDS,
//                  per-lane top-2 -> global top-4 -> margin-gated exact rescore ----
__global__ __launch_bounds__(512, 1) void vq_main(
        const float* __restrict__ x,
        const unsigned short* __restrict__ ehs,
        const unsigned short* __restrict__ el,
        const float* __restrict__ norms,
        float* __restrict__ out_idx,
        int* __restrict__ idx_ws) {

    __shared__ unsigned short ph[2][64 * 512];   // 2 x 65536 B, swizzled image
    __shared__ int   bi4[256][4];
    __shared__ float bgap[256];

    const int tid = threadIdx.x;
    const int w   = tid >> 6;                    // wave 0..7
    const int l   = tid & 63;
    const int lr  = l & 15;
    const int lg  = l >> 4;
    const int row0 = blockIdx.x * 256;

    // ---- A fragments: 2 rowsets x 16 ks, single bf16 ----
    short8 a[2][16];
    #pragma unroll
    for (int s = 0; s < 2; ++s) {
        const float* xp = x + (size_t)(row0 + w * 32 + s * 16 + lr) * DIM + lg * 8;
        #pragma unroll
        for (int ks = 0; ks < 16; ++ks) {
            float4 u  = *(const float4*)(xp + ks * 32);
            float4 v2 = *(const float4*)(xp + ks * 32 + 4);
            short8 h;
            h[0]=hi_bf(u.x);  h[1]=hi_bf(u.y);  h[2]=hi_bf(u.z);  h[3]=hi_bf(u.w);
            h[4]=hi_bf(v2.x); h[5]=hi_bf(v2.y); h[6]=hi_bf(v2.z); h[7]=hi_bf(v2.w);
            a[s][ks] = h;
        }
    }

    float t1v[2][4], t2v[2][4]; int t1i[2][4], t2i[2][4];
    #pragma unroll
    for (int s = 0; s < 2; ++s)
        #pragma unroll
        for (int r = 0; r < 4; ++r) {
            t1v[s][r]=INFINITY; t2v[s][r]=INFINITY;
            t1i[s][r]=0x7ffffffe; t2i[s][r]=0x7fffffff;
        }

    // ---- DMA stage: panel p -> buffer b (per wave: 8 instrs x 1KB) ----
    #define STAGE_PANEL(p, b)                                                   \
    {                                                                           \
        const unsigned short* gsrc = ehs + (size_t)(p) * 32768 + w * 4096 + l * 8; \
        unsigned short* ldst = &ph[b][w * 4096];                                \
        _Pragma("unroll")                                                       \
        for (int j = 0; j < 8; ++j)                                             \
            gload_lds16(gsrc + j * 512, ldst + j * 512);                        \
    }

    STAGE_PANEL(0, 0)
    __syncthreads();                             // drains DMA (vmcnt0) + barrier

    #pragma unroll 1
    for (int ct = 0; ct < 64; ++ct) {
        const int cur = ct & 1;

        // issue next panel's DMA; stays in flight until end-of-loop barrier
        if (ct < 63) STAGE_PANEL(ct + 1, cur ^ 1)

        f32x4 acc[2][4];
        #pragma unroll
        for (int s = 0; s < 2; ++s)
            #pragma unroll
            for (int cb = 0; cb < 4; ++cb) acc[s][cb] = (f32x4){0.f,0.f,0.f,0.f};

        #pragma unroll
        for (int ks = 0; ks < 16; ++ks) {
            #pragma unroll
            for (int cb = 0; cb < 4; ++cb) {
                int off = (cb * 16 + lr) * 512 + (((ks * 4 + lg) ^ (lr & 7)) * 8);
                short8 bh = *(const short8*)&ph[cur][off];
                acc[0][cb] = __builtin_amdgcn_mfma_f32_16x16x32_bf16(a[0][ks], bh, acc[0][cb], 0, 0, 0);
                acc[1][cb] = __builtin_amdgcn_mfma_f32_16x16x32_bf16(a[1][ks], bh, acc[1][cb], 0, 0, 0);
            }
        }

        // epilogue: s = ||e||^2 - 2*dot ; per-lane top-2 (ascending e)
        #pragma unroll
        for (int cb = 0; cb < 4; ++cb) {
            int e = ct * 64 + cb * 16 + lr;
            float nrm = norms[e];
            #pragma unroll
            for (int s = 0; s < 2; ++s)
                #pragma unroll
                for (int r = 0; r < 4; ++r) {
                    float sv = fmaf(-2.0f, acc[s][cb][r], nrm);
                    if (sv < t1v[s][r]) { t2v[s][r]=t1v[s][r]; t2i[s][r]=t1i[s][r]; t1v[s][r]=sv; t1i[s][r]=e; }
                    else if (sv < t2v[s][r]) { t2v[s][r]=sv; t2i[s][r]=e; }
                }
        }
        __syncthreads();   // drains panel reads (lgkm) + next-panel DMA (vmcnt)
    }
    #undef STAGE_PANEL

    // ---- per-slot: butterfly-merge per-lane top-2 lists into global top-4 ----
    #pragma unroll
    for (int s = 0; s < 2; ++s) {
        #pragma unroll
        for (int r = 0; r < 4; ++r) {
            float av[4] = { t1v[s][r], t2v[s][r], INFINITY, INFINITY };
            int   ai[4] = { t1i[s][r], t2i[s][r], 0x7ffffffe, 0x7fffffff };
            #pragma unroll
            for (int m = 1; m < 16; m <<= 1) {
                float bv[4]; int bi_[4];
                #pragma unroll
                for (int q = 0; q < 4; ++q) {
                    bv[q]  = __shfl_xor(av[q], m, 64);
                    bi_[q] = __shfl_xor(ai[q], m, 64);
                }
                float cv[4]; int ci[4];
                #pragma unroll
                for (int q = 0; q < 4; ++q) {
                    bool t = lexlt(av[q], ai[q], bv[3 - q], bi_[3 - q]);
                    cv[q] = t ? av[q] : bv[3 - q];
                    ci[q] = t ? ai[q] : bi_[3 - q];
                }
                #define CE(A,B) { if (!lexlt(cv[A],ci[A],cv[B],ci[B])) { \
                    float tv=cv[A]; cv[A]=cv[B]; cv[B]=tv; int ti=ci[A]; ci[A]=ci[B]; ci[B]=ti; } }
                CE(0,2) CE(1,3) CE(0,1) CE(2,3)
                #undef CE
                #pragma unroll
                for (int q = 0; q < 4; ++q) { av[q] = cv[q]; ai[q] = ci[q]; }
            }
            if (lr == 0) {
                int rowloc = w * 32 + s * 16 + lg * 4 + r;
                #pragma unroll
                for (int q = 0; q < 4; ++q) bi4[rowloc][q] = ai[q];
                bgap[rowloc] = av[1] - av[0];
            }
        }
    }
    __syncthreads();

    // ---- margin-gated exact rescore (x fp32, e = hi+lo) of the 4 candidates ----
    #pragma unroll 1
    for (int rr = 0; rr < 32; ++rr) {
        int rowloc = w * 32 + rr;
        int grow = row0 + rowloc;
        float gap = bgap[rowloc];
        int c0 = bi4[rowloc][0] & (NE - 1);
        if (gap > MARGIN) {
            if (l == 0) { out_idx[grow] = (float)c0; idx_ws[grow] = c0; }
            continue;
        }
        int cand[4];
        cand[0] = c0;
        cand[1] = bi4[rowloc][1] & (NE - 1);
        cand[2] = bi4[rowloc][2] & (NE - 1);
        cand[3] = bi4[rowloc][3] & (NE - 1);

        const float* xr = x + (size_t)grow * DIM + l * 8;
        float4 xa = *(const float4*)xr, xb = *(const float4*)(xr + 4);
        float xv[8] = {xa.x, xa.y, xa.z, xa.w, xb.x, xb.y, xb.z, xb.w};

        float d[4];
        #pragma unroll
        for (int q = 0; q < 4; ++q) {
            // hi from swizzled image (lane l reads granule l of code row)
            uint4 hv = *(const uint4*)&ehs[(size_t)cand[q] * 512 + ((l ^ (cand[q] & 7)) * 8)];
            uint4 lv = *(const uint4*)&el[(size_t)cand[q] * 512 + l * 8];
            const unsigned short* hp = (const unsigned short*)&hv;
            const unsigned short* lp = (const unsigned short*)&lv;
            float acc = 0.f;
            #pragma unroll
            for (int j = 0; j < 8; ++j) acc += xv[j] * (bf2f(hp[j]) + bf2f(lp[j]));
            d[q] = acc;
        }
        #pragma unroll
        for (int m = 32; m >= 1; m >>= 1) {
            #pragma unroll
            for (int q = 0; q < 4; ++q) d[q] += __shfl_xor(d[q], m, 64);
        }
        if (l == 0) {
            float bs = norms[cand[0]] - 2.0f * d[0];
            int   bi = cand[0];
            #pragma unroll
            for (int q = 1; q < 4; ++q) {
                float sq = norms[cand[q]] - 2.0f * d[q];
                if (sq < bs || (sq == bs && cand[q] < bi)) { bs = sq; bi = cand[q]; }
            }
            out_idx[grow] = (float)bi;
            idx_ws[grow] = bi;
        }
    }
}

// ---------------- gather + diff partials (hi from swizzled image + lo linear) ----------------
__global__ void gather_kernel(const float* __restrict__ x,
                              const unsigned short* __restrict__ ehs,
                              const unsigned short* __restrict__ el,
                              const int* __restrict__ idx, float* __restrict__ out_q,
                              float* __restrict__ partial) {
    __shared__ float red[256];
    const int tid = threadIdx.x;
    float local = 0.f;
    #pragma unroll 1
    for (int j = 0; j < 8; ++j) {
        int o8 = blockIdx.x * 2048 + j * 256 + tid;   // octet unit
        int r  = o8 >> 6;                             // 64 octets per row
        int c8 = o8 & 63;
        int e  = idx[r];
        uint4 hv = *(const uint4*)&ehs[(size_t)e * 512 + ((c8 ^ (e & 7)) * 8)];
        uint4 lv = *(const uint4*)&el[(size_t)e * 512 + c8 * 8];
        const unsigned short* hp = (const unsigned short*)&hv;
        const unsigned short* lp = (const unsigned short*)&lv;
        float q[8];
        #pragma unroll
        for (int k = 0; k < 8; ++k) q[k] = bf2f(hp[k]) + bf2f(lp[k]);
        float4 xa = *(const float4*)&x[(size_t)r * DIM + c8 * 8];
        float4 xb = *(const float4*)&x[(size_t)r * DIM + c8 * 8 + 4];
        *(float4*)&out_q[(size_t)r * DIM + c8 * 8]     = make_float4(q[0], q[1], q[2], q[3]);
        *(float4*)&out_q[(size_t)r * DIM + c8 * 8 + 4] = make_float4(q[4], q[5], q[6], q[7]);
        float xs[8] = {xa.x, xa.y, xa.z, xa.w, xb.x, xb.y, xb.z, xb.w};
        #pragma unroll
        for (int k = 0; k < 8; ++k) { float t = q[k] - xs[k]; local += t * t; }
    }
    red[tid] = local;
    __syncthreads();
    for (int s = 128; s > 0; s >>= 1) {
        if (tid < s) red[tid] += red[tid + s];
        __syncthreads();
    }
    if (tid == 0) partial[blockIdx.x] = red[0];
}

// ---------------- deterministic diff reduction ----------------
__global__ void diff_kernel(const float* __restrict__ partial, float* __restrict__ out_diff) {
    __shared__ float red[256];
    float s = 0.f;
    for (int i = threadIdx.x; i < 2048; i += 256) s += partial[i];
    red[threadIdx.x] = s;
    __syncthreads();
    for (int st = 128; st > 0; st >>= 1) {
        if (threadIdx.x < st) red[threadIdx.x] += red[threadIdx.x + st];
        __syncthreads();
    }
    if (threadIdx.x == 0)
        out_diff[0] = red[0] * (1.0f / ((float)NROWS * (float)DIM));
}

// ================= fallback path (R1, proven; needs only 24 KB ws) =================
#define BM 32
#define BN 64
#define BK 16
__global__ __launch_bounds__(256) void vq_kernel_fb(
        const float* __restrict__ x, const float* __restrict__ embed,
        const float* __restrict__ norms, float* __restrict__ out_q,
        float* __restrict__ out_idx, float* __restrict__ partial) {
    __shared__ float xs[BM][BK + 1];
    __shared__ float es[BK][BN];
    __shared__ float rv[BM][17];
    __shared__ int   ri[BM][17];
    __shared__ float bestv[BM];
    __shared__ int   besti[BM];
    __shared__ float red[256];
    const int tid = threadIdx.x;
    const int tc  = tid & 15;
    const int tr  = tid >> 4;
    const int row0 = blockIdx.x * BM;
    if (tid < BM) { bestv[tid] = INFINITY; besti[tid] = 0; }
    __syncthreads();
    for (int ct = 0; ct < NE / BN; ++ct) {
        float acc[2][4] = {{0.f,0.f,0.f,0.f},{0.f,0.f,0.f,0.f}};
        for (int k0 = 0; k0 < DIM; k0 += BK) {
            {
                int r = tid >> 3;
                int k = (tid & 7) * 2;
                const float* src = &x[(size_t)(row0 + r) * DIM + k0 + k];
                xs[r][k] = src[0]; xs[r][k + 1] = src[1];
            }
            {
                int r = tid >> 4;
                int c = (tid & 15) * 4;
                float4 v = *(const float4*)&embed[(size_t)(k0 + r) * NE + ct * BN + c];
                *(float4*)&es[r][c] = v;
            }
            __syncthreads();
            #pragma unroll
            for (int kk = 0; kk < BK; ++kk) {
                float a0 = xs[tr * 2 + 0][kk];
                float a1 = xs[tr * 2 + 1][kk];
                float4 b = *(const float4*)&es[kk][tc * 4];
                acc[0][0] += a0 * b.x; acc[0][1] += a0 * b.y;
                acc[0][2] += a0 * b.z; acc[0][3] += a0 * b.w;
                acc[1][0] += a1 * b.x; acc[1][1] += a1 * b.y;
                acc[1][2] += a1 * b.z; acc[1][3] += a1 * b.w;
            }
            __syncthreads();
        }
        #pragma unroll
        for (int i = 0; i < 2; ++i) {
            float bv = INFINITY; int bj = 0;
            #pragma unroll
            for (int j = 0; j < 4; ++j) {
                int e = ct * BN + tc * 4 + j;
                float s = norms[e] - 2.0f * acc[i][j];
                if (s < bv) { bv = s; bj = e; }
            }
            rv[tr * 2 + i][tc] = bv; ri[tr * 2 + i][tc] = bj;
        }
        __syncthreads();
        if (tid < BM) {
            float bv = bestv[tid]; int bi = besti[tid];
            #pragma unroll
            for (int t = 0; t < 16; ++t) {
                float v = rv[tid][t];
                if (v < bv) { bv = v; bi = ri[tid][t]; }
            }
            bestv[tid] = bv; besti[tid] = bi;
        }
        __syncthreads();
    }
    if (tid < BM) out_idx[row0 + tid] = (float)besti[tid];
    __syncthreads();
    float local = 0.f;
    for (int i = tid; i < BM * DIM; i += 256) {
        int r = i >> 9;
        int d = i & (DIM - 1);
        int e = besti[r];
        float q  = embed[(size_t)d * NE + e];
        float xv = x[(size_t)(row0 + r) * DIM + d];
        out_q[(size_t)(row0 + r) * DIM + d] = q;
        float t = q - xv;
        local += t * t;
    }
    red[tid] = local;
    __syncthreads();
    for (int s = 128; s > 0; s >>= 1) {
        if (tid < s) red[tid] += red[tid + s];
        __syncthreads();
    }
    if (tid == 0) partial[blockIdx.x] = red[0];
}

extern "C" void kernel_launch(void* const* d_in, const int* in_sizes, int n_in,
                              void* d_out, int out_size, void* d_ws, size_t ws_size,
                              hipStream_t stream) {
    (void)in_sizes; (void)n_in; (void)out_size;
    const float* x     = (const float*)d_in[0];
    const float* embed = (const float*)d_in[1];

    float* out      = (float*)d_out;
    float* out_q    = out;
    float* out_diff = out + (size_t)NROWS * DIM;
    float* out_idx  = out_diff + 1;

    const size_t NEED = 4194304ull * 2 + 16384 + 8192 + 262144;  // ehs+el+norms+partial+idx

    char* wsb = (char*)d_ws;
    if (ws_size >= NEED) {
        unsigned short* ehs     = (unsigned short*)wsb;               // 4194304 B
        unsigned short* el      = (unsigned short*)(wsb + 4194304);   // 4194304 B
        float*          norms   = (float*)(wsb + 8388608);            //   16384 B
        float*          partial = (float*)(wsb + 8404992);            //    8192 B
        int*            idx     = (int*)(wsb + 8413184);              //  262144 B

        norms_kernel<<<NE / 256, 256, 0, stream>>>(embed, norms);
        prep_kernel<<<dim3(64, 8), 256, 0, stream>>>(embed, ehs, el);
        vq_main<<<256, 512, 0, stream>>>(x, ehs, el, norms, out_idx, idx);
        gather_kernel<<<2048, 256, 0, stream>>>(x, ehs, el, idx, out_q, partial);
        diff_kernel<<<1, 256, 0, stream>>>(partial, out_diff);
    } else {
        float* norms   = (float*)wsb;            // 16384 B
        float* partial = norms + NE;             //  8192 B
        norms_kernel<<<NE / 256, 256, 0, stream>>>(embed, norms);
        vq_kernel_fb<<<NROWS / BM, 256, 0, stream>>>(x, embed, norms, out_q, out_idx, partial);
        diff_kernel<<<1, 256, 0, stream>>>(partial, out_diff);
    }
}